// Round 1
// baseline (1022.464 us; speedup 1.0000x reference)
//
#include <hip/hip_runtime.h>
#include <hip/hip_bf16.h>

#define SEQ   2048
#define INSZ  5760
#define NQ    4096
#define NKV   512
#define NQKV  5120
#define HQ    64
#define HKV   8
#define HD    64
#define HID   2880
#define HIDP  2944   // 23*128, padded rows for woT

typedef __attribute__((ext_vector_type(8))) short bf16x8;
typedef __attribute__((ext_vector_type(4))) float f32x4;

__device__ __forceinline__ unsigned short f2bf(float x) {
  __hip_bfloat16 b = __float2bfloat16(x);
  return __builtin_bit_cast(unsigned short, b);
}
__device__ __forceinline__ float bf2f(unsigned short u) {
  return __bfloat162float(__builtin_bit_cast(__hip_bfloat16, u));
}

// ---------------- fp32 -> bf16 elementwise convert ----------------
__global__ void k_convert(const float* __restrict__ src, unsigned short* __restrict__ dst, int n) {
  int stride = gridDim.x * blockDim.x * 4;
  for (int idx = (blockIdx.x * blockDim.x + threadIdx.x) * 4; idx < n; idx += stride) {
    float4 v = *(const float4*)(src + idx);
    ushort4 o;
    o.x = f2bf(v.x); o.y = f2bf(v.y); o.z = f2bf(v.z); o.w = f2bf(v.w);
    *(ushort4*)(dst + idx) = o;
  }
}

// ---------------- transpose-convert: src fp32 [K][N] -> dst bf16 [N][K] ----------------
// grid = (K/32, Npad/32); rows n >= N written as 0 (padding).
__global__ void k_tconv(const float* __restrict__ src, unsigned short* __restrict__ dst,
                        int K, int N) {
  __shared__ float tile[32][33];
  int k0 = blockIdx.x * 32, n0 = blockIdx.y * 32;
  int r = threadIdx.x >> 5, c = threadIdx.x & 31;
#pragma unroll
  for (int i = 0; i < 4; i++) {
    int row = i * 8 + r;
    float v = (n0 + c < N) ? src[(size_t)(k0 + row) * N + n0 + c] : 0.f;
    tile[row][c] = v;
  }
  __syncthreads();
#pragma unroll
  for (int i = 0; i < 4; i++) {
    int n = n0 + i * 8 + r;
    dst[(size_t)n * K + k0 + c] = f2bf(tile[c][i * 8 + r]);
  }
}

// ---------------- GEMM: C[M][N] = A[M][K] * BT[N][K]^T  (m97 structure) ----------------
// 128x128 tile, BK=32, 4 waves (2x2), 16x16x32 bf16 MFMA, global_load_lds width 16.
template <typename OutT>
__global__ __launch_bounds__(256) void k_gemm_bt(
    const unsigned short* __restrict__ A,   // M x K  bf16
    const unsigned short* __restrict__ BT,  // Npad x K  bf16
    OutT* __restrict__ C, int Kdim, int Ncols, int ldc) {
  __shared__ unsigned short sA[128 * 32];
  __shared__ unsigned short sB[128 * 32];
  int tid = threadIdx.x, wid = tid >> 6, lane = tid & 63;
  int bm = blockIdx.x, bn = blockIdx.y;
  const unsigned short* Ab = A + (size_t)bm * 128 * Kdim;
  const unsigned short* Bb = BT + (size_t)bn * 128 * Kdim;
  f32x4 acc[4][4];
#pragma unroll
  for (int i = 0; i < 4; i++)
#pragma unroll
    for (int j = 0; j < 4; j++) acc[i][j] = f32x4{0.f, 0.f, 0.f, 0.f};
  int wr = (wid >> 1) * 64, wc = (wid & 1) * 64;
  int srow = lane >> 2;         // row within 16-row chunk
  int selem = (lane & 3) * 8;   // bf16 element offset within 32-elem row
  int rbase = lane & 15, koff = (lane >> 4) * 8;

  for (int kt = 0; kt < Kdim; kt += 32) {
    __syncthreads();  // previous tile's compute done before overwrite
#pragma unroll
    for (int ch2 = 0; ch2 < 2; ++ch2) {
      int chunk = wid * 2 + ch2;
      const unsigned short* ga = Ab + (size_t)(chunk * 16 + srow) * Kdim + kt + selem;
      const unsigned short* gb = Bb + (size_t)(chunk * 16 + srow) * Kdim + kt + selem;
      __builtin_amdgcn_global_load_lds(
          (const __attribute__((address_space(1))) void*)ga,
          (__attribute__((address_space(3))) void*)(sA + chunk * 512), 16, 0, 0);
      __builtin_amdgcn_global_load_lds(
          (const __attribute__((address_space(1))) void*)gb,
          (__attribute__((address_space(3))) void*)(sB + chunk * 512), 16, 0, 0);
    }
    __syncthreads();  // compiler drains vmcnt(0) before barrier -> LDS ready
    bf16x8 a[4], b[4];
#pragma unroll
    for (int i = 0; i < 4; i++)
      a[i] = *(const bf16x8*)(sA + (wr + i * 16 + rbase) * 32 + koff);
#pragma unroll
    for (int j = 0; j < 4; j++)
      b[j] = *(const bf16x8*)(sB + (wc + j * 16 + rbase) * 32 + koff);
#pragma unroll
    for (int i = 0; i < 4; i++)
#pragma unroll
      for (int j = 0; j < 4; j++)
        acc[i][j] = __builtin_amdgcn_mfma_f32_16x16x32_bf16(a[i], b[j], acc[i][j], 0, 0, 0);
  }
  // epilogue: C layout col=lane&15, row=(lane>>4)*4+reg
  int rw = (lane >> 4) * 4, cl = lane & 15;
#pragma unroll
  for (int i = 0; i < 4; i++)
#pragma unroll
    for (int j = 0; j < 4; j++) {
      int col = bn * 128 + wc + j * 16 + cl;
      if (col < Ncols) {
#pragma unroll
        for (int r = 0; r < 4; r++) {
          int row = bm * 128 + wr + i * 16 + rw + r;
          float v = acc[i][j][r];
          if constexpr (sizeof(OutT) == 2)
            C[(size_t)row * ldc + col] = (OutT)f2bf(v);
          else
            C[(size_t)row * ldc + col] = v;
        }
      }
    }
}

// ---------------- RoPE in-place on Q (cols 0..4095) and K (cols 4096..4607) ----------------
__global__ void k_rope(unsigned short* __restrict__ qkv, const float* __restrict__ cosb,
                       const float* __restrict__ sinb) {
  int s = blockIdx.x;
  const float* cs = cosb + s * HD;
  const float* sn = sinb + s * HD;
  unsigned short* row = qkv + (size_t)s * NQKV;
  for (int idx = threadIdx.x; idx < (HQ + HKV) * 32; idx += blockDim.x) {
    int head = idx >> 5, dp = idx & 31;
    unsigned short* base = row + (head < HQ ? head * 64 : NQ + (head - HQ) * 64);
    float x1 = bf2f(base[dp]), x2 = bf2f(base[dp + 32]);
    float o1 = x1 * cs[dp] - x2 * sn[dp];
    float o2 = x2 * cs[dp + 32] + x1 * sn[dp + 32];
    base[dp] = f2bf(o1);
    base[dp + 32] = f2bf(o2);
  }
}

// ---------------- V transpose: qkv V cols -> vt[hkv][d][s] ----------------
__global__ void k_vtrans(const unsigned short* __restrict__ qkv, unsigned short* __restrict__ vt) {
  __shared__ unsigned short tile[64 * 66];
  int st = blockIdx.x, hk = blockIdx.y;
  int s0 = st * 64, t = threadIdx.x;
#pragma unroll
  for (int i = 0; i < 16; i++) {
    int e = i * 256 + t;
    int sl = e >> 6, d = e & 63;
    tile[d * 66 + sl] = qkv[(size_t)(s0 + sl) * NQKV + NQ + NKV + hk * 64 + d];
  }
  __syncthreads();
#pragma unroll
  for (int i = 0; i < 16; i++) {
    int e = i * 256 + t;
    int d = e >> 6, sl = e & 63;
    vt[(size_t)(hk * 64 + d) * SEQ + s0 + sl] = tile[d * 66 + sl];
  }
}

// ---------------- Flash attention ----------------
// grid (HQ, SEQ/64); 4 waves/block, each wave owns 16 q rows, KV tiles of 64.
__global__ __launch_bounds__(256) void k_attn(
    const unsigned short* __restrict__ qkv, const unsigned short* __restrict__ vt,
    unsigned short* __restrict__ out) {
  __shared__ unsigned short sP[4 * 16 * 72];  // per-wave P buffer, row stride 72 (pad)
  int tid = threadIdx.x, wid = tid >> 6, lane = tid & 63;
  int head = blockIdx.x, qt = blockIdx.y;
  int hkv = head >> 3;
  int q0 = qt * 64 + wid * 16;
  int rbase = lane & 15, koff = (lane >> 4) * 8;

  const unsigned short* qrow = qkv + (size_t)(q0 + rbase) * NQKV + head * 64;
  bf16x8 qa0 = *(const bf16x8*)(qrow + koff);
  bf16x8 qa1 = *(const bf16x8*)(qrow + 32 + koff);

  const unsigned short* Kbase = qkv + NQ + hkv * 64;      // + s*NQKV
  const unsigned short* Vbase = vt + (size_t)hkv * 64 * SEQ;  // [d][s]

  f32x4 o[4];
#pragma unroll
  for (int i = 0; i < 4; i++) o[i] = f32x4{0.f, 0.f, 0.f, 0.f};
  float m[4] = {-3e38f, -3e38f, -3e38f, -3e38f};
  float lp[4] = {0.f, 0.f, 0.f, 0.f};
  const float SL2 = 0.125f * 1.44269504f;  // scale * log2(e)
  unsigned short* myP = sP + wid * 16 * 72;

  for (int kv = 0; kv < SEQ; kv += 64) {
    f32x4 sc[4];
#pragma unroll
    for (int c = 0; c < 4; c++) sc[c] = f32x4{0.f, 0.f, 0.f, 0.f};
#pragma unroll
    for (int c = 0; c < 4; c++) {
      const unsigned short* krow = Kbase + (size_t)(kv + c * 16 + rbase) * NQKV;
      bf16x8 kb0 = *(const bf16x8*)(krow + koff);
      bf16x8 kb1 = *(const bf16x8*)(krow + 32 + koff);
      sc[c] = __builtin_amdgcn_mfma_f32_16x16x32_bf16(qa0, kb0, sc[c], 0, 0, 0);
      sc[c] = __builtin_amdgcn_mfma_f32_16x16x32_bf16(qa1, kb1, sc[c], 0, 0, 0);
    }
    // online softmax (everything in exp2 domain; t2 = s*scale*log2e)
    float corr[4];
#pragma unroll
    for (int j = 0; j < 4; j++) {
      float t2 = fmaxf(fmaxf(sc[0][j], sc[1][j]), fmaxf(sc[2][j], sc[3][j])) * SL2;
#pragma unroll
      for (int d = 1; d < 16; d <<= 1) t2 = fmaxf(t2, __shfl_xor(t2, d, 64));
      float mn = fmaxf(m[j], t2);
      corr[j] = exp2f(m[j] - mn);
      m[j] = mn;
    }
    float psum[4] = {0.f, 0.f, 0.f, 0.f};
#pragma unroll
    for (int c = 0; c < 4; c++) {
#pragma unroll
      for (int j = 0; j < 4; j++) {
        float p = exp2f(sc[c][j] * SL2 - m[j]);
        psum[j] += p;
        myP[((lane >> 4) * 4 + j) * 72 + c * 16 + (lane & 15)] = f2bf(p);
      }
    }
#pragma unroll
    for (int j = 0; j < 4; j++) lp[j] = lp[j] * corr[j] + psum[j];
#pragma unroll
    for (int i = 0; i < 4; i++) {
      f32x4 t = o[i];
      t[0] *= corr[0]; t[1] *= corr[1]; t[2] *= corr[2]; t[3] *= corr[3];
      o[i] = t;
    }
    // PV: read P back as A-fragments (wave-local, compiler inserts lgkmcnt)
    bf16x8 pa0 = *(const bf16x8*)(myP + rbase * 72 + koff);
    bf16x8 pa1 = *(const bf16x8*)(myP + rbase * 72 + 32 + koff);
#pragma unroll
    for (int dt = 0; dt < 4; dt++) {
      const unsigned short* vrow = Vbase + (size_t)(dt * 16 + rbase) * SEQ + kv;
      bf16x8 vb0 = *(const bf16x8*)(vrow + koff);
      bf16x8 vb1 = *(const bf16x8*)(vrow + 32 + koff);
      o[dt] = __builtin_amdgcn_mfma_f32_16x16x32_bf16(pa0, vb0, o[dt], 0, 0, 0);
      o[dt] = __builtin_amdgcn_mfma_f32_16x16x32_bf16(pa1, vb1, o[dt], 0, 0, 0);
    }
  }
  // finalize
#pragma unroll
  for (int j = 0; j < 4; j++) {
#pragma unroll
    for (int d = 1; d < 16; d <<= 1) lp[j] += __shfl_xor(lp[j], d, 64);
    lp[j] = 1.0f / lp[j];
  }
#pragma unroll
  for (int dt = 0; dt < 4; dt++)
#pragma unroll
    for (int j = 0; j < 4; j++) {
      int row = q0 + (lane >> 4) * 4 + j;
      int col = head * 64 + dt * 16 + (lane & 15);
      out[(size_t)row * NQ + col] = f2bf(o[dt][j] * lp[j]);
    }
}

// ---------------- launch ----------------
extern "C" void kernel_launch(void* const* d_in, const int* in_sizes, int n_in,
                              void* d_out, int out_size, void* d_ws, size_t ws_size,
                              hipStream_t stream) {
  const float* hidden = (const float*)d_in[0];
  const float* cosb = (const float*)d_in[1];
  const float* sinb = (const float*)d_in[2];
  const float* wq = (const float*)d_in[3];
  const float* wk = (const float*)d_in[4];
  const float* wv = (const float*)d_in[5];
  const float* wo = (const float*)d_in[6];
  float* out = (float*)d_out;

  unsigned short* hb = (unsigned short*)d_ws;               // 2048*5760
  unsigned short* qkv = hb + (size_t)SEQ * INSZ;            // 2048*5120
  unsigned short* wqkvT = qkv + (size_t)SEQ * NQKV;         // 5120*5760
  unsigned short* woT = wqkvT + (size_t)NQKV * INSZ;        // 2944*4096
  unsigned short* vt = woT + (size_t)HIDP * NQ;             // 512*2048
  unsigned short* attn = vt + (size_t)NKV * SEQ;            // 2048*4096

  k_convert<<<dim3(1024), dim3(256), 0, stream>>>(hidden, hb, SEQ * INSZ);
  k_tconv<<<dim3(INSZ / 32, NQ / 32), dim3(256), 0, stream>>>(wq, wqkvT, INSZ, NQ);
  k_tconv<<<dim3(INSZ / 32, NKV / 32), dim3(256), 0, stream>>>(
      wk, wqkvT + (size_t)NQ * INSZ, INSZ, NKV);
  k_tconv<<<dim3(INSZ / 32, NKV / 32), dim3(256), 0, stream>>>(
      wv, wqkvT + (size_t)(NQ + NKV) * INSZ, INSZ, NKV);
  k_tconv<<<dim3(NQ / 32, HIDP / 32), dim3(256), 0, stream>>>(wo, woT, NQ, HID);

  k_gemm_bt<unsigned short><<<dim3(SEQ / 128, NQKV / 128), dim3(256), 0, stream>>>(
      hb, wqkvT, qkv, INSZ, NQKV, NQKV);
  k_rope<<<dim3(SEQ), dim3(256), 0, stream>>>(qkv, cosb, sinb);
  k_vtrans<<<dim3(SEQ / 64, HKV), dim3(256), 0, stream>>>(qkv, vt);
  k_attn<<<dim3(HQ, SEQ / 64), dim3(256), 0, stream>>>(qkv, vt, attn);
  k_gemm_bt<float><<<dim3(SEQ / 128, (HID + 127) / 128), dim3(256), 0, stream>>>(
      attn, woT, out, NQ, HID, HID);
}

// Round 2
// 766.478 us; speedup vs baseline: 1.3340x; 1.3340x over previous
//
#include <hip/hip_runtime.h>
#include <hip/hip_bf16.h>

#define SEQ   2048
#define INSZ  5760
#define NQ    4096
#define NKV   512
#define NQKV  5120
#define HQ    64
#define HKV   8
#define HD    64
#define HID   2880
#define HIDP  2944   // 23*128, padded rows for woT

typedef __attribute__((ext_vector_type(8))) short bf16x8;
typedef __attribute__((ext_vector_type(4))) float f32x4;

__device__ __forceinline__ unsigned short f2bf(float x) {
  __hip_bfloat16 b = __float2bfloat16(x);
  return __builtin_bit_cast(unsigned short, b);
}
__device__ __forceinline__ float bf2f(unsigned short u) {
  return __bfloat162float(__builtin_bit_cast(__hip_bfloat16, u));
}

// ---------------- fp32 -> bf16 elementwise convert ----------------
__global__ void k_convert(const float* __restrict__ src, unsigned short* __restrict__ dst, int n) {
  int stride = gridDim.x * blockDim.x * 4;
  for (int idx = (blockIdx.x * blockDim.x + threadIdx.x) * 4; idx < n; idx += stride) {
    float4 v = *(const float4*)(src + idx);
    ushort4 o;
    o.x = f2bf(v.x); o.y = f2bf(v.y); o.z = f2bf(v.z); o.w = f2bf(v.w);
    *(ushort4*)(dst + idx) = o;
  }
}

// ---------------- transpose-convert: src fp32 [K][N] -> dst bf16 [N][K] ----------------
__global__ void k_tconv(const float* __restrict__ src, unsigned short* __restrict__ dst,
                        int K, int N) {
  __shared__ float tile[32][33];
  int k0 = blockIdx.x * 32, n0 = blockIdx.y * 32;
  int r = threadIdx.x >> 5, c = threadIdx.x & 31;
#pragma unroll
  for (int i = 0; i < 4; i++) {
    int row = i * 8 + r;
    float v = (n0 + c < N) ? src[(size_t)(k0 + row) * N + n0 + c] : 0.f;
    tile[row][c] = v;
  }
  __syncthreads();
#pragma unroll
  for (int i = 0; i < 4; i++) {
    int n = n0 + i * 8 + r;
    dst[(size_t)n * K + k0 + c] = f2bf(tile[c][i * 8 + r]);
  }
}

// ---------------- GEMM: C[M][N] = A[M][K] * BT[N][K]^T  (m97 structure) ----------------
template <typename OutT>
__global__ __launch_bounds__(256) void k_gemm_bt(
    const unsigned short* __restrict__ A,   // M x K  bf16
    const unsigned short* __restrict__ BT,  // Npad x K  bf16
    OutT* __restrict__ C, int Kdim, int Ncols, int ldc) {
  __shared__ unsigned short sA[128 * 32];
  __shared__ unsigned short sB[128 * 32];
  int tid = threadIdx.x, wid = tid >> 6, lane = tid & 63;
  int bm = blockIdx.x, bn = blockIdx.y;
  const unsigned short* Ab = A + (size_t)bm * 128 * Kdim;
  const unsigned short* Bb = BT + (size_t)bn * 128 * Kdim;
  f32x4 acc[4][4];
#pragma unroll
  for (int i = 0; i < 4; i++)
#pragma unroll
    for (int j = 0; j < 4; j++) acc[i][j] = f32x4{0.f, 0.f, 0.f, 0.f};
  int wr = (wid >> 1) * 64, wc = (wid & 1) * 64;
  int srow = lane >> 2;
  int selem = (lane & 3) * 8;
  int rbase = lane & 15, koff = (lane >> 4) * 8;

  for (int kt = 0; kt < Kdim; kt += 32) {
    __syncthreads();
#pragma unroll
    for (int ch2 = 0; ch2 < 2; ++ch2) {
      int chunk = wid * 2 + ch2;
      const unsigned short* ga = Ab + (size_t)(chunk * 16 + srow) * Kdim + kt + selem;
      const unsigned short* gb = Bb + (size_t)(chunk * 16 + srow) * Kdim + kt + selem;
      __builtin_amdgcn_global_load_lds(
          (const __attribute__((address_space(1))) void*)ga,
          (__attribute__((address_space(3))) void*)(sA + chunk * 512), 16, 0, 0);
      __builtin_amdgcn_global_load_lds(
          (const __attribute__((address_space(1))) void*)gb,
          (__attribute__((address_space(3))) void*)(sB + chunk * 512), 16, 0, 0);
    }
    __syncthreads();
    bf16x8 a[4], b[4];
#pragma unroll
    for (int i = 0; i < 4; i++)
      a[i] = *(const bf16x8*)(sA + (wr + i * 16 + rbase) * 32 + koff);
#pragma unroll
    for (int j = 0; j < 4; j++)
      b[j] = *(const bf16x8*)(sB + (wc + j * 16 + rbase) * 32 + koff);
#pragma unroll
    for (int i = 0; i < 4; i++)
#pragma unroll
      for (int j = 0; j < 4; j++)
        acc[i][j] = __builtin_amdgcn_mfma_f32_16x16x32_bf16(a[i], b[j], acc[i][j], 0, 0, 0);
  }
  int rw = (lane >> 4) * 4, cl = lane & 15;
#pragma unroll
  for (int i = 0; i < 4; i++)
#pragma unroll
    for (int j = 0; j < 4; j++) {
      int col = bn * 128 + wc + j * 16 + cl;
      if (col < Ncols) {
#pragma unroll
        for (int r = 0; r < 4; r++) {
          int row = bm * 128 + wr + i * 16 + rw + r;
          float v = acc[i][j][r];
          if constexpr (sizeof(OutT) == 2)
            C[(size_t)row * ldc + col] = (OutT)f2bf(v);
          else
            C[(size_t)row * ldc + col] = v;
        }
      }
    }
}

// ---------------- RoPE in-place ----------------
__global__ void k_rope(unsigned short* __restrict__ qkv, const float* __restrict__ cosb,
                       const float* __restrict__ sinb) {
  int s = blockIdx.x;
  const float* cs = cosb + s * HD;
  const float* sn = sinb + s * HD;
  unsigned short* row = qkv + (size_t)s * NQKV;
  for (int idx = threadIdx.x; idx < (HQ + HKV) * 32; idx += blockDim.x) {
    int head = idx >> 5, dp = idx & 31;
    unsigned short* base = row + (head < HQ ? head * 64 : NQ + (head - HQ) * 64);
    float x1 = bf2f(base[dp]), x2 = bf2f(base[dp + 32]);
    float o1 = x1 * cs[dp] - x2 * sn[dp];
    float o2 = x2 * cs[dp + 32] + x1 * sn[dp + 32];
    base[dp] = f2bf(o1);
    base[dp + 32] = f2bf(o2);
  }
}

// ---------------- V transpose: qkv V cols -> vt[hkv][d][s] ----------------
__global__ void k_vtrans(const unsigned short* __restrict__ qkv, unsigned short* __restrict__ vt) {
  __shared__ unsigned short tile[64 * 66];
  int st = blockIdx.x, hk = blockIdx.y;
  int s0 = st * 64, t = threadIdx.x;
#pragma unroll
  for (int i = 0; i < 16; i++) {
    int e = i * 256 + t;
    int sl = e >> 6, d = e & 63;
    tile[d * 66 + sl] = qkv[(size_t)(s0 + sl) * NQKV + NQ + NKV + hk * 64 + d];
  }
  __syncthreads();
#pragma unroll
  for (int i = 0; i < 16; i++) {
    int e = i * 256 + t;
    int d = e >> 6, sl = e & 63;
    vt[(size_t)(hk * 64 + d) * SEQ + s0 + sl] = tile[d * 66 + sl];
  }
}

// ---------------- Flash attention (LDS-staged, double-buffered, swizzled) ----------------
// grid (HQ, SEQ/64); 4 waves/block, each wave 16 q rows, KV tiles of 64.
// K,V tiles staged via global_load_lds (linear dest) with inverse-swizzled global
// source slot; reads apply slot ^= (row&7) -> conflict-free ds_read_b128.
__global__ __launch_bounds__(256) void k_attn(
    const unsigned short* __restrict__ qkv, const unsigned short* __restrict__ vt,
    unsigned short* __restrict__ out) {
  __shared__ unsigned short sK[2][64 * 64];   // [s][d], swizzled, 8KB each
  __shared__ unsigned short sV[2][64 * 64];   // [d][s], swizzled, 8KB each
  __shared__ unsigned short sP[4 * 16 * 64];  // per-wave P, swizzled, 8KB
  int tid = threadIdx.x, wid = tid >> 6, lane = tid & 63;
  int head = blockIdx.x, qt = blockIdx.y;
  int hkv = head >> 3;
  int q0 = qt * 64 + wid * 16;
  int rbase = lane & 15, lg = lane >> 4;
  int koff = lg * 8;

  // Q fragments (held in registers for the whole kernel)
  const unsigned short* qrow = qkv + (size_t)(q0 + rbase) * NQKV + head * 64;
  bf16x8 qa0 = *(const bf16x8*)(qrow + koff);
  bf16x8 qa1 = *(const bf16x8*)(qrow + 32 + koff);

  // staging geometry: one global_load_lds covers 8 rows x 128B; lane l writes
  // LDS base + l*16 (linear). Source slot pre-swizzled so read-side slot^(row&7) works.
  int r8 = lane >> 3;                       // row within 8-row chunk
  int srcslot = ((lane & 7) ^ r8) * 16;     // inverse-swizzled byte slot in row

  // read-side per-lane byte offsets (row = <c|dt>*16 + rbase; (row&7) == rbase&7)
  int sw = rbase & 7;
  int off0 = rbase * 128 + (lg ^ sw) * 16;         // elements koff..+7
  int off1 = rbase * 128 + ((lg + 4) ^ sw) * 16;   // elements 32+koff..+7

  f32x4 o[4];
#pragma unroll
  for (int i = 0; i < 4; i++) o[i] = f32x4{0.f, 0.f, 0.f, 0.f};
  float m[4] = {-3e38f, -3e38f, -3e38f, -3e38f};
  float lp[4] = {0.f, 0.f, 0.f, 0.f};
  const float SL2 = 0.125f * 1.44269504f;  // scale * log2(e)
  char* myP = (char*)(sP + wid * 16 * 64);

  // P write addressing: row = lg*4+j, col = c*16+rbase
  int sbase = rbase >> 3;
  int pw_base[4], pw_x[4];
#pragma unroll
  for (int j = 0; j < 4; j++) {
    int prow = lg * 4 + j;
    pw_base[j] = prow * 128 + (rbase & 7) * 2;
    pw_x[j] = prow & 7;
  }

#define STAGE_KV(buf, kv)                                                            \
  {                                                                                  \
    _Pragma("unroll") for (int ch = 0; ch < 2; ++ch) {                               \
      int r0 = (wid * 2 + ch) * 8;                                                   \
      const char* gk =                                                               \
          (const char*)(qkv + (size_t)((kv) + r0 + r8) * NQKV + NQ + hkv * 64) +     \
          srcslot;                                                                   \
      __builtin_amdgcn_global_load_lds(                                              \
          (const __attribute__((address_space(1))) void*)gk,                         \
          (__attribute__((address_space(3))) void*)(&sK[buf][r0 * 64]), 16, 0, 0);   \
      const char* gv =                                                               \
          (const char*)(vt + (size_t)(hkv * 64 + r0 + r8) * SEQ + (kv)) + srcslot;   \
      __builtin_amdgcn_global_load_lds(                                              \
          (const __attribute__((address_space(1))) void*)gv,                         \
          (__attribute__((address_space(3))) void*)(&sV[buf][r0 * 64]), 16, 0, 0);   \
    }                                                                                \
  }

  STAGE_KV(0, 0);
  __syncthreads();
  int cur = 0;

  for (int kvt = 0; kvt < SEQ / 64; ++kvt) {
    if (kvt + 1 < SEQ / 64) STAGE_KV(cur ^ 1, (kvt + 1) * 64);

    const char* kb = (const char*)&sK[cur][0];
    const char* vb = (const char*)&sV[cur][0];

    // QK^T
    f32x4 sc[4];
#pragma unroll
    for (int c = 0; c < 4; c++) sc[c] = f32x4{0.f, 0.f, 0.f, 0.f};
#pragma unroll
    for (int c = 0; c < 4; c++) {
      bf16x8 kb0 = *(const bf16x8*)(kb + c * 2048 + off0);
      bf16x8 kb1 = *(const bf16x8*)(kb + c * 2048 + off1);
      sc[c] = __builtin_amdgcn_mfma_f32_16x16x32_bf16(qa0, kb0, sc[c], 0, 0, 0);
      sc[c] = __builtin_amdgcn_mfma_f32_16x16x32_bf16(qa1, kb1, sc[c], 0, 0, 0);
    }

    // row max (exp2 domain)
    float t2[4];
#pragma unroll
    for (int j = 0; j < 4; j++) {
      float t = fmaxf(fmaxf(sc[0][j], sc[1][j]), fmaxf(sc[2][j], sc[3][j])) * SL2;
#pragma unroll
      for (int d = 1; d < 16; d <<= 1) t = fmaxf(t, __shfl_xor(t, d, 64));
      t2[j] = t;
    }
    // defer-max (T13): only rescale when some row max grows past THR=8
    bool need = (t2[0] > m[0] + 8.f) || (t2[1] > m[1] + 8.f) ||
                (t2[2] > m[2] + 8.f) || (t2[3] > m[3] + 8.f);
    if (__any(need)) {
      float corr[4];
#pragma unroll
      for (int j = 0; j < 4; j++) {
        float mn = fmaxf(m[j], t2[j]);
        corr[j] = exp2f(m[j] - mn);
        m[j] = mn;
        lp[j] *= corr[j];
      }
#pragma unroll
      for (int dt = 0; dt < 4; dt++) {
        f32x4 t = o[dt];
        t[0] *= corr[0]; t[1] *= corr[1]; t[2] *= corr[2]; t[3] *= corr[3];
        o[dt] = t;
      }
    }

    // P = exp2(sc*SL2 - m), write to swizzled LDS P buffer
    float psum[4] = {0.f, 0.f, 0.f, 0.f};
#pragma unroll
    for (int c = 0; c < 4; c++) {
#pragma unroll
      for (int j = 0; j < 4; j++) {
        float p = exp2f(sc[c][j] * SL2 - m[j]);
        psum[j] += p;
        *(unsigned short*)(myP + pw_base[j] + ((c * 2 + sbase) ^ pw_x[j]) * 16) = f2bf(p);
      }
    }
#pragma unroll
    for (int j = 0; j < 4; j++) lp[j] += psum[j];

    // PV
    bf16x8 pa0 = *(const bf16x8*)(myP + off0);
    bf16x8 pa1 = *(const bf16x8*)(myP + off1);
#pragma unroll
    for (int dt = 0; dt < 4; dt++) {
      bf16x8 vb0 = *(const bf16x8*)(vb + dt * 2048 + off0);
      bf16x8 vb1 = *(const bf16x8*)(vb + dt * 2048 + off1);
      o[dt] = __builtin_amdgcn_mfma_f32_16x16x32_bf16(pa0, vb0, o[dt], 0, 0, 0);
      o[dt] = __builtin_amdgcn_mfma_f32_16x16x32_bf16(pa1, vb1, o[dt], 0, 0, 0);
    }

    __syncthreads();
    cur ^= 1;
  }

  // finalize
#pragma unroll
  for (int j = 0; j < 4; j++) {
#pragma unroll
    for (int d = 1; d < 16; d <<= 1) lp[j] += __shfl_xor(lp[j], d, 64);
    lp[j] = 1.0f / lp[j];
  }
#pragma unroll
  for (int dt = 0; dt < 4; dt++)
#pragma unroll
    for (int j = 0; j < 4; j++) {
      int row = q0 + lg * 4 + j;
      int col = head * 64 + dt * 16 + rbase;
      out[(size_t)row * NQ + col] = f2bf(o[dt][j] * lp[j]);
    }
#undef STAGE_KV
}

// ---------------- launch ----------------
extern "C" void kernel_launch(void* const* d_in, const int* in_sizes, int n_in,
                              void* d_out, int out_size, void* d_ws, size_t ws_size,
                              hipStream_t stream) {
  const float* hidden = (const float*)d_in[0];
  const float* cosb = (const float*)d_in[1];
  const float* sinb = (const float*)d_in[2];
  const float* wq = (const float*)d_in[3];
  const float* wk = (const float*)d_in[4];
  const float* wv = (const float*)d_in[5];
  const float* wo = (const float*)d_in[6];
  float* out = (float*)d_out;

  unsigned short* hb = (unsigned short*)d_ws;               // 2048*5760
  unsigned short* qkv = hb + (size_t)SEQ * INSZ;            // 2048*5120
  unsigned short* wqkvT = qkv + (size_t)SEQ * NQKV;         // 5120*5760
  unsigned short* woT = wqkvT + (size_t)NQKV * INSZ;        // 2944*4096
  unsigned short* vt = woT + (size_t)HIDP * NQ;             // 512*2048
  unsigned short* attn = vt + (size_t)NKV * SEQ;            // 2048*4096

  k_convert<<<dim3(1024), dim3(256), 0, stream>>>(hidden, hb, SEQ * INSZ);
  k_tconv<<<dim3(INSZ / 32, NQ / 32), dim3(256), 0, stream>>>(wq, wqkvT, INSZ, NQ);
  k_tconv<<<dim3(INSZ / 32, NKV / 32), dim3(256), 0, stream>>>(
      wk, wqkvT + (size_t)NQ * INSZ, INSZ, NKV);
  k_tconv<<<dim3(INSZ / 32, NKV / 32), dim3(256), 0, stream>>>(
      wv, wqkvT + (size_t)(NQ + NKV) * INSZ, INSZ, NKV);
  k_tconv<<<dim3(NQ / 32, HIDP / 32), dim3(256), 0, stream>>>(wo, woT, NQ, HID);

  k_gemm_bt<unsigned short><<<dim3(SEQ / 128, NQKV / 128), dim3(256), 0, stream>>>(
      hb, wqkvT, qkv, INSZ, NQKV, NQKV);
  k_rope<<<dim3(SEQ), dim3(256), 0, stream>>>(qkv, cosb, sinb);
  k_vtrans<<<dim3(SEQ / 64, HKV), dim3(256), 0, stream>>>(qkv, vt);
  k_attn<<<dim3(HQ, SEQ / 64), dim3(256), 0, stream>>>(qkv, vt, attn);
  k_gemm_bt<float><<<dim3(SEQ / 128, (HID + 127) / 128), dim3(256), 0, stream>>>(
      attn, woT, out, NQ, HID, HID);
}

// Round 4
// 673.117 us; speedup vs baseline: 1.5190x; 1.1387x over previous
//
#include <hip/hip_runtime.h>
#include <hip/hip_bf16.h>

#define SEQ   2048
#define INSZ  5760
#define NQ    4096
#define NKV   512
#define NQKV  5120
#define HQ    64
#define HKV   8
#define HD    64
#define HID   2880
#define HIDP  2944   // 23*128, padded rows for woT

typedef __attribute__((ext_vector_type(8))) short bf16x8;
typedef __attribute__((ext_vector_type(4))) float f32x4;
typedef __attribute__((ext_vector_type(16))) float f32x16;
typedef unsigned int u32;

__device__ __forceinline__ unsigned short f2bf(float x) {
  __hip_bfloat16 b = __float2bfloat16(x);
  return __builtin_bit_cast(unsigned short, b);
}
__device__ __forceinline__ float bf2f(unsigned short u) {
  return __bfloat162float(__builtin_bit_cast(__hip_bfloat16, u));
}
__device__ __forceinline__ float exp2_hw(float x) {
  float r;
  asm("v_exp_f32 %0, %1" : "=v"(r) : "v"(x));
  return r;
}
__device__ __forceinline__ u32 cvt_pk_bf16(float lo, float hi) {
  u32 r;
  asm("v_cvt_pk_bf16_f32 %0, %1, %2" : "=v"(r) : "v"(lo), "v"(hi));
  return r;
}

// ---------------- fp32 -> bf16 elementwise convert ----------------
__global__ void k_convert(const float* __restrict__ src, unsigned short* __restrict__ dst, int n) {
  int stride = gridDim.x * blockDim.x * 4;
  for (int idx = (blockIdx.x * blockDim.x + threadIdx.x) * 4; idx < n; idx += stride) {
    float4 v = *(const float4*)(src + idx);
    ushort4 o;
    o.x = f2bf(v.x); o.y = f2bf(v.y); o.z = f2bf(v.z); o.w = f2bf(v.w);
    *(ushort4*)(dst + idx) = o;
  }
}

// ---------------- transpose-convert: src fp32 [K][N] -> dst bf16 [N][K] ----------------
__global__ void k_tconv(const float* __restrict__ src, unsigned short* __restrict__ dst,
                        int K, int N) {
  __shared__ float tile[32][33];
  int k0 = blockIdx.x * 32, n0 = blockIdx.y * 32;
  int r = threadIdx.x >> 5, c = threadIdx.x & 31;
#pragma unroll
  for (int i = 0; i < 4; i++) {
    int row = i * 8 + r;
    float v = (n0 + c < N) ? src[(size_t)(k0 + row) * N + n0 + c] : 0.f;
    tile[row][c] = v;
  }
  __syncthreads();
#pragma unroll
  for (int i = 0; i < 4; i++) {
    int n = n0 + i * 8 + r;
    dst[(size_t)n * K + k0 + c] = f2bf(tile[c][i * 8 + r]);
  }
}

// ---------------- GEMM: C[M][N] = A[M][K] * BT[N][K]^T  (m97 structure + XCD swizzle) ----
template <typename OutT>
__global__ __launch_bounds__(256) void k_gemm_bt(
    const unsigned short* __restrict__ A,   // M x K  bf16
    const unsigned short* __restrict__ BT,  // Npad x K  bf16
    OutT* __restrict__ C, int Kdim, int Ncols, int ldc) {
  __shared__ unsigned short sA[128 * 32];
  __shared__ unsigned short sB[128 * 32];
  int tid = threadIdx.x, wid = tid >> 6, lane = tid & 63;
  // bijective XCD swizzle (m204): contiguous chunk of linear ids per XCD
  int gx = gridDim.x;
  int nwg = gx * gridDim.y;
  int lin = blockIdx.y * gx + blockIdx.x;
  int qn = nwg >> 3, rn = nwg & 7;
  int xcd = lin & 7, idx = lin >> 3;
  int swz = (xcd < rn ? xcd * (qn + 1) : rn * (qn + 1) + (xcd - rn) * qn) + idx;
  int bm = swz % gx, bn = swz / gx;
  const unsigned short* Ab = A + (size_t)bm * 128 * Kdim;
  const unsigned short* Bb = BT + (size_t)bn * 128 * Kdim;
  f32x4 acc[4][4];
#pragma unroll
  for (int i = 0; i < 4; i++)
#pragma unroll
    for (int j = 0; j < 4; j++) acc[i][j] = f32x4{0.f, 0.f, 0.f, 0.f};
  int wr = (wid >> 1) * 64, wc = (wid & 1) * 64;
  int srow = lane >> 2;
  int selem = (lane & 3) * 8;
  int rbase = lane & 15, koff = (lane >> 4) * 8;

  for (int kt = 0; kt < Kdim; kt += 32) {
    __syncthreads();
#pragma unroll
    for (int ch2 = 0; ch2 < 2; ++ch2) {
      int chunk = wid * 2 + ch2;
      const unsigned short* ga = Ab + (size_t)(chunk * 16 + srow) * Kdim + kt + selem;
      const unsigned short* gb = Bb + (size_t)(chunk * 16 + srow) * Kdim + kt + selem;
      __builtin_amdgcn_global_load_lds(
          (const __attribute__((address_space(1))) void*)ga,
          (__attribute__((address_space(3))) void*)(sA + chunk * 512), 16, 0, 0);
      __builtin_amdgcn_global_load_lds(
          (const __attribute__((address_space(1))) void*)gb,
          (__attribute__((address_space(3))) void*)(sB + chunk * 512), 16, 0, 0);
    }
    __syncthreads();
    bf16x8 a[4], b[4];
#pragma unroll
    for (int i = 0; i < 4; i++)
      a[i] = *(const bf16x8*)(sA + (wr + i * 16 + rbase) * 32 + koff);
#pragma unroll
    for (int j = 0; j < 4; j++)
      b[j] = *(const bf16x8*)(sB + (wc + j * 16 + rbase) * 32 + koff);
#pragma unroll
    for (int i = 0; i < 4; i++)
#pragma unroll
      for (int j = 0; j < 4; j++)
        acc[i][j] = __builtin_amdgcn_mfma_f32_16x16x32_bf16(a[i], b[j], acc[i][j], 0, 0, 0);
  }
  int rw = (lane >> 4) * 4, cl = lane & 15;
#pragma unroll
  for (int i = 0; i < 4; i++)
#pragma unroll
    for (int j = 0; j < 4; j++) {
      int col = bn * 128 + wc + j * 16 + cl;
      if (col < Ncols) {
#pragma unroll
        for (int r = 0; r < 4; r++) {
          int row = bm * 128 + wr + i * 16 + rw + r;
          float v = acc[i][j][r];
          if constexpr (sizeof(OutT) == 2)
            C[(size_t)row * ldc + col] = (OutT)f2bf(v);
          else
            C[(size_t)row * ldc + col] = v;
        }
      }
    }
}

// ---------------- RoPE in-place ----------------
__global__ void k_rope(unsigned short* __restrict__ qkv, const float* __restrict__ cosb,
                       const float* __restrict__ sinb) {
  int s = blockIdx.x;
  const float* cs = cosb + s * HD;
  const float* sn = sinb + s * HD;
  unsigned short* row = qkv + (size_t)s * NQKV;
  for (int idx = threadIdx.x; idx < (HQ + HKV) * 32; idx += blockDim.x) {
    int head = idx >> 5, dp = idx & 31;
    unsigned short* base = row + (head < HQ ? head * 64 : NQ + (head - HQ) * 64);
    float x1 = bf2f(base[dp]), x2 = bf2f(base[dp + 32]);
    float o1 = x1 * cs[dp] - x2 * sn[dp];
    float o2 = x2 * cs[dp + 32] + x1 * sn[dp + 32];
    base[dp] = f2bf(o1);
    base[dp + 32] = f2bf(o2);
  }
}

// ---------------- V transpose: qkv V cols -> vt[hkv][d][s] ----------------
__global__ void k_vtrans(const unsigned short* __restrict__ qkv, unsigned short* __restrict__ vt) {
  __shared__ unsigned short tile[64 * 66];
  int st = blockIdx.x, hk = blockIdx.y;
  int s0 = st * 64, t = threadIdx.x;
#pragma unroll
  for (int i = 0; i < 16; i++) {
    int e = i * 256 + t;
    int sl = e >> 6, d = e & 63;
    tile[d * 66 + sl] = qkv[(size_t)(s0 + sl) * NQKV + NQ + NKV + hk * 64 + d];
  }
  __syncthreads();
#pragma unroll
  for (int i = 0; i < 16; i++) {
    int e = i * 256 + t;
    int d = e >> 6, sl = e & 63;
    vt[(size_t)(hk * 64 + d) * SEQ + s0 + sl] = tile[d * 66 + sl];
  }
}

// ---------------- Flash attention: swapped-operand 32x32x16, P in registers ----------------
// grid (HQ, SEQ/128); 4 waves/block, each wave 32 q rows, KV tiles of 64.
// S^T = mfma(K, Q): lane holds P[q=lane&31][kv-half per hi]; O^T = mfma(V^T, P^T).
__global__ __launch_bounds__(256) void k_attn(
    const unsigned short* __restrict__ qkv, const unsigned short* __restrict__ vt,
    unsigned short* __restrict__ out) {
  __shared__ unsigned short smem[16384];  // 32KB: K dbuf [2][64*64] @0, V dbuf @8192
  int tid = threadIdx.x, wid = tid >> 6, lane = tid & 63;
  int head = blockIdx.x, qt = blockIdx.y;
  int hkv = head >> 3;
  int q = lane & 31, h = lane >> 5;
  int q0w = qt * 128 + wid * 32;
  const float SL2 = 0.125f * 1.44269504f;  // scale * log2(e)

  // Q B-frags (persist): Q[q0w+q][ks*16 + h*8 + e]
  bf16x8 qf[4];
  {
    const unsigned short* qrow = qkv + (size_t)(q0w + q) * NQKV + head * 64 + h * 8;
#pragma unroll
    for (int ks = 0; ks < 4; ks++) qf[ks] = *(const bf16x8*)(qrow + ks * 16);
  }

  // staging geometry (pre-swizzled source, linear LDS dest)
  int r8 = lane >> 3;
  int srcslot = ((lane & 7) ^ r8) * 16;  // bytes
  int sw = q & 7;                        // (t*32+q)&7 == q&7

#define STAGE_KV(buf, kv)                                                            \
  {                                                                                  \
    _Pragma("unroll") for (int ch = 0; ch < 2; ++ch) {                               \
      int r0 = (wid * 2 + ch) * 8;                                                   \
      const char* gk =                                                               \
          (const char*)(qkv + (size_t)((kv) + r0 + r8) * NQKV + NQ + hkv * 64) +     \
          srcslot;                                                                   \
      __builtin_amdgcn_global_load_lds(                                              \
          (const __attribute__((address_space(1))) void*)gk,                         \
          (__attribute__((address_space(3))) void*)(smem + (buf)*4096 + r0 * 64),    \
          16, 0, 0);                                                                 \
      const char* gv =                                                               \
          (const char*)(vt + (size_t)(hkv * 64 + r0 + r8) * SEQ + (kv)) + srcslot;   \
      __builtin_amdgcn_global_load_lds(                                              \
          (const __attribute__((address_space(1))) void*)gv,                         \
          (__attribute__((address_space(3))) void*)(smem + 8192 + (buf)*4096 +       \
                                                    r0 * 64),                        \
          16, 0, 0);                                                                 \
    }                                                                                \
  }

  f32x16 o0, o1;
#pragma unroll
  for (int r = 0; r < 16; r++) { o0[r] = 0.f; o1[r] = 0.f; }
  float m = -3e38f, lp = 0.f;

  STAGE_KV(0, 0);
  __syncthreads();
  int cur = 0;

  for (int kvt = 0; kvt < SEQ / 64; ++kvt) {
    if (kvt + 1 < SEQ / 64) STAGE_KV(cur ^ 1, (kvt + 1) * 64);
    const char* kb = (const char*)(smem + cur * 4096);
    const char* vb = (const char*)(smem + 8192 + cur * 4096);

    // QK^T swapped: st[t] = S^T tile (kv rows t*32.., q cols)
    f32x16 st0, st1;
#pragma unroll
    for (int r = 0; r < 16; r++) { st0[r] = 0.f; st1[r] = 0.f; }
    {
      bf16x8 kf[4];
#pragma unroll
      for (int ks = 0; ks < 4; ks++)
        kf[ks] = *(const bf16x8*)(kb + q * 128 + (((2 * ks + h) ^ sw) << 4));
#pragma unroll
      for (int ks = 0; ks < 4; ks++)
        st0 = __builtin_amdgcn_mfma_f32_32x32x16_bf16(kf[ks], qf[ks], st0, 0, 0, 0);
#pragma unroll
      for (int ks = 0; ks < 4; ks++)
        kf[ks] = *(const bf16x8*)(kb + (32 + q) * 128 + (((2 * ks + h) ^ sw) << 4));
#pragma unroll
      for (int ks = 0; ks < 4; ks++)
        st1 = __builtin_amdgcn_mfma_f32_32x32x16_bf16(kf[ks], qf[ks], st1, 0, 0, 0);
    }

    // row max: in-lane tree over 32 + 1 cross-hi shfl
    float tmx[16];
#pragma unroll
    for (int r = 0; r < 16; r++) tmx[r] = fmaxf(st0[r], st1[r]);
#pragma unroll
    for (int s = 8; s >= 1; s >>= 1)
#pragma unroll
      for (int r = 0; r < 8; r++)
        if (r < s) tmx[r] = fmaxf(tmx[r], tmx[r + s]);
    float mx = fmaxf(tmx[0], __shfl_xor(tmx[0], 32, 64));
    float t2 = mx * SL2;

    // defer-max (T13, THR=8 in log2 domain)
    if (__any(t2 > m + 8.f)) {
      float mn = fmaxf(m, t2);
      float corr = exp2_hw(m - mn);
      m = mn;
      lp *= corr;
#pragma unroll
      for (int r = 0; r < 16; r++) { o0[r] *= corr; o1[r] *= corr; }
    }

    // P = exp2(st*SL2 - m), in place; psum with 4 accumulators
    float psa[4] = {0.f, 0.f, 0.f, 0.f};
#pragma unroll
    for (int r = 0; r < 16; r++) {
      float e0 = exp2_hw(fmaf(st0[r], SL2, -m));
      float e1 = exp2_hw(fmaf(st1[r], SL2, -m));
      st0[r] = e0; st1[r] = e1;
      psa[r & 3] += e0 + e1;
    }
    lp += (psa[0] + psa[1]) + (psa[2] + psa[3]);

    // pack P to bf16 words: pk[t*8+w] = regs (2w, 2w+1) of tile t
    u32 pk[16];
#pragma unroll
    for (int w = 0; w < 8; w++) {
      pk[w] = cvt_pk_bf16(st0[2 * w], st0[2 * w + 1]);
      pk[8 + w] = cvt_pk_bf16(st1[2 * w], st1[2 * w + 1]);
    }

    // P^T B-frags via cross-hi exchange: frag[ks] elem e -> P[q][ks*16 + h*8 + e]
    bf16x8 pf[4];
#pragma unroll
    for (int ks = 0; ks < 4; ks++) {
      int base = 8 * (ks >> 1) + 4 * (ks & 1);
      u32 wA0 = pk[base], wA1 = pk[base + 1], wB0 = pk[base + 2], wB1 = pk[base + 3];
      u32 keep0 = h ? wB0 : wA0, keep1 = h ? wB1 : wA1;
      u32 send0 = h ? wA0 : wB0, send1 = h ? wA1 : wB1;
      u32 rc0 = (u32)__shfl_xor((int)send0, 32, 64);
      u32 rc1 = (u32)__shfl_xor((int)send1, 32, 64);
      union { u32 w[4]; bf16x8 v; } u;
      u.w[0] = h ? rc0 : keep0;
      u.w[1] = h ? rc1 : keep1;
      u.w[2] = h ? keep0 : rc0;
      u.w[3] = h ? keep1 : rc1;
      pf[ks] = u.v;
    }

    // PV swapped: O^T[d][q] += V^T * P^T
    {
      bf16x8 vf[4];
#pragma unroll
      for (int ks = 0; ks < 4; ks++)
        vf[ks] = *(const bf16x8*)(vb + q * 128 + (((2 * ks + h) ^ sw) << 4));
#pragma unroll
      for (int ks = 0; ks < 4; ks++)
        o0 = __builtin_amdgcn_mfma_f32_32x32x16_bf16(vf[ks], pf[ks], o0, 0, 0, 0);
#pragma unroll
      for (int ks = 0; ks < 4; ks++)
        vf[ks] = *(const bf16x8*)(vb + (32 + q) * 128 + (((2 * ks + h) ^ sw) << 4));
#pragma unroll
      for (int ks = 0; ks < 4; ks++)
        o1 = __builtin_amdgcn_mfma_f32_32x32x16_bf16(vf[ks], pf[ks], o1, 0, 0, 0);
    }

    __syncthreads();
    cur ^= 1;
  }

  // ---- epilogue: normalize, transpose via LDS, coalesced store ----
  float lpt = lp + __shfl_xor(lp, 32, 64);
  float inv = 1.0f / lpt;

  unsigned short* ot = smem + wid * (32 * 72);  // per-wave [32 q][72] bf16 tile
#pragma unroll
  for (int w = 0; w < 8; w++) {
    int reg = 2 * w;
    int dbase = (reg & 3) + 8 * (reg >> 2) + 4 * h;
    u32 p0 = cvt_pk_bf16(o0[reg] * inv, o0[reg + 1] * inv);
    u32 p1 = cvt_pk_bf16(o1[reg] * inv, o1[reg + 1] * inv);
    *(u32*)(ot + q * 72 + dbase) = p0;
    *(u32*)(ot + q * 72 + 32 + dbase) = p1;
  }
  __syncthreads();
  int row = lane >> 1, halfc = lane & 1;
  const unsigned short* src = ot + row * 72 + halfc * 32;
  unsigned short* dst = out + (size_t)(q0w + row) * NQ + head * 64 + halfc * 32;
#pragma unroll
  for (int c = 0; c < 4; c++)
    *(bf16x8*)(dst + c * 8) = *(const bf16x8*)(src + c * 8);
#undef STAGE_KV
}

// ---------------- launch ----------------
extern "C" void kernel_launch(void* const* d_in, const int* in_sizes, int n_in,
                              void* d_out, int out_size, void* d_ws, size_t ws_size,
                              hipStream_t stream) {
  const float* hidden = (const float*)d_in[0];
  const float* cosb = (const float*)d_in[1];
  const float* sinb = (const float*)d_in[2];
  const float* wq = (const float*)d_in[3];
  const float* wk = (const float*)d_in[4];
  const float* wv = (const float*)d_in[5];
  const float* wo = (const float*)d_in[6];
  float* out = (float*)d_out;

  unsigned short* hb = (unsigned short*)d_ws;               // 2048*5760
  unsigned short* qkv = hb + (size_t)SEQ * INSZ;            // 2048*5120
  unsigned short* wqkvT = qkv + (size_t)SEQ * NQKV;         // 5120*5760
  unsigned short* woT = wqkvT + (size_t)NQKV * INSZ;        // 2944*4096
  unsigned short* vt = woT + (size_t)HIDP * NQ;             // 512*2048
  unsigned short* attn = vt + (size_t)NKV * SEQ;            // 2048*4096

  k_convert<<<dim3(1024), dim3(256), 0, stream>>>(hidden, hb, SEQ * INSZ);
  k_tconv<<<dim3(INSZ / 32, NQ / 32), dim3(256), 0, stream>>>(wq, wqkvT, INSZ, NQ);
  k_tconv<<<dim3(INSZ / 32, NKV / 32), dim3(256), 0, stream>>>(
      wk, wqkvT + (size_t)NQ * INSZ, INSZ, NKV);
  k_tconv<<<dim3(INSZ / 32, NKV / 32), dim3(256), 0, stream>>>(
      wv, wqkvT + (size_t)(NQ + NKV) * INSZ, INSZ, NKV);
  k_tconv<<<dim3(NQ / 32, HIDP / 32), dim3(256), 0, stream>>>(wo, woT, NQ, HID);

  k_gemm_bt<unsigned short><<<dim3(SEQ / 128, NQKV / 128), dim3(256), 0, stream>>>(
      hb, wqkvT, qkv, INSZ, NQKV, NQKV);
  k_rope<<<dim3(SEQ), dim3(256), 0, stream>>>(qkv, cosb, sinb);
  k_vtrans<<<dim3(SEQ / 64, HKV), dim3(256), 0, stream>>>(qkv, vt);
  k_attn<<<dim3(HQ, SEQ / 128), dim3(256), 0, stream>>>(qkv, vt, attn);
  k_gemm_bt<float><<<dim3(SEQ / 128, (HID + 127) / 128), dim3(256), 0, stream>>>(
      attn, woT, out, NQ, HID, HID);
}

// Round 6
// 624.663 us; speedup vs baseline: 1.6368x; 1.0776x over previous
//
#include <hip/hip_runtime.h>
#include <hip/hip_bf16.h>

#define SEQ   2048
#define INSZ  5760
#define NQ    4096
#define NKV   512
#define NQKV  5120
#define HQ    64
#define HKV   8
#define HD    64
#define HID   2880
#define HIDP  2944   // 23*128, padded rows for woT

typedef __attribute__((ext_vector_type(8))) short bf16x8;
typedef __attribute__((ext_vector_type(4))) float f32x4;
typedef __attribute__((ext_vector_type(16))) float f32x16;
typedef unsigned int u32;

__device__ __forceinline__ unsigned short f2bf(float x) {
  __hip_bfloat16 b = __float2bfloat16(x);
  return __builtin_bit_cast(unsigned short, b);
}
__device__ __forceinline__ float bf2f(unsigned short u) {
  return __bfloat162float(__builtin_bit_cast(__hip_bfloat16, u));
}
__device__ __forceinline__ float exp2_hw(float x) {
  float r;
  asm("v_exp_f32 %0, %1" : "=v"(r) : "v"(x));
  return r;
}
__device__ __forceinline__ u32 cvt_pk_bf16(float lo, float hi) {
  u32 r;
  asm("v_cvt_pk_bf16_f32 %0, %1, %2" : "=v"(r) : "v"(lo), "v"(hi));
  return r;
}

// ---------------- fp32 -> bf16 elementwise convert ----------------
__global__ void k_convert(const float* __restrict__ src, unsigned short* __restrict__ dst, int n) {
  int stride = gridDim.x * blockDim.x * 4;
  for (int idx = (blockIdx.x * blockDim.x + threadIdx.x) * 4; idx < n; idx += stride) {
    float4 v = *(const float4*)(src + idx);
    ushort4 o;
    o.x = f2bf(v.x); o.y = f2bf(v.y); o.z = f2bf(v.z); o.w = f2bf(v.w);
    *(ushort4*)(dst + idx) = o;
  }
}

// ---------------- transpose-convert: src fp32 [K][N] -> dst bf16 [N][K] ----------------
// 64(k) x 32(n) tiles; vectorized 16B stores along K. grid=(K/64, Npad/32).
__global__ void k_tconv(const float* __restrict__ src, unsigned short* __restrict__ dst,
                        int K, int N) {
  __shared__ float tile[64][33];
  int k0 = blockIdx.x * 64, n0 = blockIdx.y * 32;
  int tid = threadIdx.x;
  int r = tid >> 5, c = tid & 31;
#pragma unroll
  for (int i = 0; i < 8; i++) {
    int row = i * 8 + r;
    tile[row][c] = (n0 + c < N) ? src[(size_t)(k0 + row) * N + n0 + c] : 0.f;
  }
  __syncthreads();
  int n = tid >> 3, kk = (tid & 7) * 8;
  union { u32 w[4]; bf16x8 v; } u;
#pragma unroll
  for (int j = 0; j < 4; j++)
    u.w[j] = cvt_pk_bf16(tile[kk + 2 * j][n], tile[kk + 2 * j + 1][n]);
  *(bf16x8*)(dst + (size_t)(n0 + n) * K + k0 + kk) = u.v;
}

// ---------------- GEMM: C[M][N] = A[M][K] * BT[N][K]^T ----------------
// m97 structure upgraded to 2-phase double-buffered staging (T3 minimum):
// prologue stage; loop { STAGE(next); ds_read+MFMA(cur); barrier; } — 1 barrier/K-step.
template <typename OutT>
__global__ __launch_bounds__(256) void k_gemm_bt(
    const unsigned short* __restrict__ A,   // M x K  bf16
    const unsigned short* __restrict__ BT,  // Npad x K  bf16
    OutT* __restrict__ C, int Kdim, int Ncols, int ldc) {
  __shared__ unsigned short sA[2][128 * 32];
  __shared__ unsigned short sB[2][128 * 32];
  int tid = threadIdx.x, wid = tid >> 6, lane = tid & 63;
  // bijective XCD swizzle (m204)
  int gx = gridDim.x;
  int nwg = gx * gridDim.y;
  int lin = blockIdx.y * gx + blockIdx.x;
  int qn = nwg >> 3, rn = nwg & 7;
  int xcd = lin & 7, idx = lin >> 3;
  int swz = (xcd < rn ? xcd * (qn + 1) : rn * (qn + 1) + (xcd - rn) * qn) + idx;
  int bm = swz % gx, bn = swz / gx;
  const unsigned short* Ab = A + (size_t)bm * 128 * Kdim;
  const unsigned short* Bb = BT + (size_t)bn * 128 * Kdim;
  f32x4 acc[4][4];
#pragma unroll
  for (int i = 0; i < 4; i++)
#pragma unroll
    for (int j = 0; j < 4; j++) acc[i][j] = f32x4{0.f, 0.f, 0.f, 0.f};
  int wr = (wid >> 1) * 64, wc = (wid & 1) * 64;
  int srow = lane >> 2;
  int selem = (lane & 3) * 8;
  int rbase = lane & 15, koff = (lane >> 4) * 8;

#define G_STAGE(buf, kt)                                                             \
  {                                                                                  \
    _Pragma("unroll") for (int ch2 = 0; ch2 < 2; ++ch2) {                            \
      int chunk = wid * 2 + ch2;                                                     \
      const unsigned short* ga = Ab + (size_t)(chunk * 16 + srow) * Kdim + (kt) + selem; \
      const unsigned short* gb = Bb + (size_t)(chunk * 16 + srow) * Kdim + (kt) + selem; \
      __builtin_amdgcn_global_load_lds(                                              \
          (const __attribute__((address_space(1))) void*)ga,                         \
          (__attribute__((address_space(3))) void*)(&sA[buf][chunk * 512]), 16, 0, 0); \
      __builtin_amdgcn_global_load_lds(                                              \
          (const __attribute__((address_space(1))) void*)gb,                         \
          (__attribute__((address_space(3))) void*)(&sB[buf][chunk * 512]), 16, 0, 0); \
    }                                                                                \
  }

  int nt = Kdim >> 5;
  G_STAGE(0, 0);
  __syncthreads();
  int cur = 0;
  for (int t = 0; t < nt; ++t) {
    if (t + 1 < nt) G_STAGE(cur ^ 1, (t + 1) * 32);
    bf16x8 a[4], b[4];
#pragma unroll
    for (int i = 0; i < 4; i++)
      a[i] = *(const bf16x8*)(&sA[cur][(wr + i * 16 + rbase) * 32 + koff]);
#pragma unroll
    for (int j = 0; j < 4; j++)
      b[j] = *(const bf16x8*)(&sB[cur][(wc + j * 16 + rbase) * 32 + koff]);
#pragma unroll
    for (int i = 0; i < 4; i++)
#pragma unroll
      for (int j = 0; j < 4; j++)
        acc[i][j] = __builtin_amdgcn_mfma_f32_16x16x32_bf16(a[i], b[j], acc[i][j], 0, 0, 0);
    __syncthreads();  // next tile staged; all reads of cur done before overwrite
    cur ^= 1;
  }
#undef G_STAGE
  int rw = (lane >> 4) * 4, cl = lane & 15;
#pragma unroll
  for (int i = 0; i < 4; i++)
#pragma unroll
    for (int j = 0; j < 4; j++) {
      int col = bn * 128 + wc + j * 16 + cl;
      if (col < Ncols) {
#pragma unroll
        for (int r = 0; r < 4; r++) {
          int row = bm * 128 + wr + i * 16 + rw + r;
          float v = acc[i][j][r];
          if constexpr (sizeof(OutT) == 2)
            C[(size_t)row * ldc + col] = (OutT)f2bf(v);
          else
            C[(size_t)row * ldc + col] = v;
        }
      }
    }
}

// ---------------- RoPE in-place ----------------
__global__ void k_rope(unsigned short* __restrict__ qkv, const float* __restrict__ cosb,
                       const float* __restrict__ sinb) {
  int s = blockIdx.x;
  const float* cs = cosb + s * HD;
  const float* sn = sinb + s * HD;
  unsigned short* row = qkv + (size_t)s * NQKV;
  for (int idx = threadIdx.x; idx < (HQ + HKV) * 32; idx += blockDim.x) {
    int head = idx >> 5, dp = idx & 31;
    unsigned short* base = row + (head < HQ ? head * 64 : NQ + (head - HQ) * 64);
    float x1 = bf2f(base[dp]), x2 = bf2f(base[dp + 32]);
    float o1 = x1 * cs[dp] - x2 * sn[dp];
    float o2 = x2 * cs[dp + 32] + x1 * sn[dp + 32];
    base[dp] = f2bf(o1);
    base[dp + 32] = f2bf(o2);
  }
}

// ---------------- V transpose: qkv V cols -> vt[hkv][d][s] ----------------
__global__ void k_vtrans(const unsigned short* __restrict__ qkv, unsigned short* __restrict__ vt) {
  __shared__ unsigned short tile[64 * 66];
  int st = blockIdx.x, hk = blockIdx.y;
  int s0 = st * 64, t = threadIdx.x;
#pragma unroll
  for (int i = 0; i < 16; i++) {
    int e = i * 256 + t;
    int sl = e >> 6, d = e & 63;
    tile[d * 66 + sl] = qkv[(size_t)(s0 + sl) * NQKV + NQ + NKV + hk * 64 + d];
  }
  __syncthreads();
#pragma unroll
  for (int i = 0; i < 16; i++) {
    int e = i * 256 + t;
    int d = e >> 6, sl = e & 63;
    vt[(size_t)(hk * 64 + d) * SEQ + s0 + sl] = tile[d * 66 + sl];
  }
}

// ---------------- Flash attention: swapped-operand 32x32x16, P in registers ----------------
__global__ __launch_bounds__(256) void k_attn(
    const unsigned short* __restrict__ qkv, const unsigned short* __restrict__ vt,
    unsigned short* __restrict__ out) {
  __shared__ unsigned short smem[16384];  // 32KB: K dbuf [2][64*64] @0, V dbuf @8192
  int tid = threadIdx.x, wid = tid >> 6, lane = tid & 63;
  int head = blockIdx.x, qt = blockIdx.y;
  int hkv = head >> 3;
  int q = lane & 31, h = lane >> 5;
  int q0w = qt * 128 + wid * 32;
  const float SL2 = 0.125f * 1.44269504f;  // scale * log2(e)

  bf16x8 qf[4];
  {
    const unsigned short* qrow = qkv + (size_t)(q0w + q) * NQKV + head * 64 + h * 8;
#pragma unroll
    for (int ks = 0; ks < 4; ks++) qf[ks] = *(const bf16x8*)(qrow + ks * 16);
  }

  int r8 = lane >> 3;
  int srcslot = ((lane & 7) ^ r8) * 16;
  int sw = q & 7;

#define STAGE_KV(buf, kv)                                                            \
  {                                                                                  \
    _Pragma("unroll") for (int ch = 0; ch < 2; ++ch) {                               \
      int r0 = (wid * 2 + ch) * 8;                                                   \
      const char* gk =                                                               \
          (const char*)(qkv + (size_t)((kv) + r0 + r8) * NQKV + NQ + hkv * 64) +     \
          srcslot;                                                                   \
      __builtin_amdgcn_global_load_lds(                                              \
          (const __attribute__((address_space(1))) void*)gk,                         \
          (__attribute__((address_space(3))) void*)(smem + (buf)*4096 + r0 * 64),    \
          16, 0, 0);                                                                 \
      const char* gv =                                                               \
          (const char*)(vt + (size_t)(hkv * 64 + r0 + r8) * SEQ + (kv)) + srcslot;   \
      __builtin_amdgcn_global_load_lds(                                              \
          (const __attribute__((address_space(1))) void*)gv,                         \
          (__attribute__((address_space(3))) void*)(smem + 8192 + (buf)*4096 +       \
                                                    r0 * 64),                        \
          16, 0, 0);                                                                 \
    }                                                                                \
  }

  f32x16 o0, o1;
#pragma unroll
  for (int r = 0; r < 16; r++) { o0[r] = 0.f; o1[r] = 0.f; }
  float m = -3e38f, lp = 0.f;

  STAGE_KV(0, 0);
  __syncthreads();
  int cur = 0;

  for (int kvt = 0; kvt < SEQ / 64; ++kvt) {
    if (kvt + 1 < SEQ / 64) STAGE_KV(cur ^ 1, (kvt + 1) * 64);
    const char* kb = (const char*)(smem + cur * 4096);
    const char* vb = (const char*)(smem + 8192 + cur * 4096);

    f32x16 st0, st1;
#pragma unroll
    for (int r = 0; r < 16; r++) { st0[r] = 0.f; st1[r] = 0.f; }
    {
      bf16x8 kf[4];
#pragma unroll
      for (int ks = 0; ks < 4; ks++)
        kf[ks] = *(const bf16x8*)(kb + q * 128 + (((2 * ks + h) ^ sw) << 4));
#pragma unroll
      for (int ks = 0; ks < 4; ks++)
        st0 = __builtin_amdgcn_mfma_f32_32x32x16_bf16(kf[ks], qf[ks], st0, 0, 0, 0);
#pragma unroll
      for (int ks = 0; ks < 4; ks++)
        kf[ks] = *(const bf16x8*)(kb + (32 + q) * 128 + (((2 * ks + h) ^ sw) << 4));
#pragma unroll
      for (int ks = 0; ks < 4; ks++)
        st1 = __builtin_amdgcn_mfma_f32_32x32x16_bf16(kf[ks], qf[ks], st1, 0, 0, 0);
    }

    float tmx[16];
#pragma unroll
    for (int r = 0; r < 16; r++) tmx[r] = fmaxf(st0[r], st1[r]);
#pragma unroll
    for (int s = 8; s >= 1; s >>= 1)
#pragma unroll
      for (int r = 0; r < 8; r++)
        if (r < s) tmx[r] = fmaxf(tmx[r], tmx[r + s]);
    float mx = fmaxf(tmx[0], __shfl_xor(tmx[0], 32, 64));
    float t2 = mx * SL2;

    if (__any(t2 > m + 8.f)) {
      float mn = fmaxf(m, t2);
      float corr = exp2_hw(m - mn);
      m = mn;
      lp *= corr;
#pragma unroll
      for (int r = 0; r < 16; r++) { o0[r] *= corr; o1[r] *= corr; }
    }

    float psa[4] = {0.f, 0.f, 0.f, 0.f};
#pragma unroll
    for (int r = 0; r < 16; r++) {
      float e0 = exp2_hw(fmaf(st0[r], SL2, -m));
      float e1 = exp2_hw(fmaf(st1[r], SL2, -m));
      st0[r] = e0; st1[r] = e1;
      psa[r & 3] += e0 + e1;
    }
    lp += (psa[0] + psa[1]) + (psa[2] + psa[3]);

    u32 pk[16];
#pragma unroll
    for (int w = 0; w < 8; w++) {
      pk[w] = cvt_pk_bf16(st0[2 * w], st0[2 * w + 1]);
      pk[8 + w] = cvt_pk_bf16(st1[2 * w], st1[2 * w + 1]);
    }

    bf16x8 pf[4];
#pragma unroll
    for (int ks = 0; ks < 4; ks++) {
      int base = 8 * (ks >> 1) + 4 * (ks & 1);
      u32 wA0 = pk[base], wA1 = pk[base + 1], wB0 = pk[base + 2], wB1 = pk[base + 3];
      u32 keep0 = h ? wB0 : wA0, keep1 = h ? wB1 : wA1;
      u32 send0 = h ? wA0 : wB0, send1 = h ? wA1 : wB1;
      u32 rc0 = (u32)__shfl_xor((int)send0, 32, 64);
      u32 rc1 = (u32)__shfl_xor((int)send1, 32, 64);
      union { u32 w[4]; bf16x8 v; } u;
      u.w[0] = h ? rc0 : keep0;
      u.w[1] = h ? rc1 : keep1;
      u.w[2] = h ? keep0 : rc0;
      u.w[3] = h ? keep1 : rc1;
      pf[ks] = u.v;
    }

    {
      bf16x8 vf[4];
#pragma unroll
      for (int ks = 0; ks < 4; ks++)
        vf[ks] = *(const bf16x8*)(vb + q * 128 + (((2 * ks + h) ^ sw) << 4));
#pragma unroll
      for (int ks = 0; ks < 4; ks++)
        o0 = __builtin_amdgcn_mfma_f32_32x32x16_bf16(vf[ks], pf[ks], o0, 0, 0, 0);
#pragma unroll
      for (int ks = 0; ks < 4; ks++)
        vf[ks] = *(const bf16x8*)(vb + (32 + q) * 128 + (((2 * ks + h) ^ sw) << 4));
#pragma unroll
      for (int ks = 0; ks < 4; ks++)
        o1 = __builtin_amdgcn_mfma_f32_32x32x16_bf16(vf[ks], pf[ks], o1, 0, 0, 0);
    }

    __syncthreads();
    cur ^= 1;
  }

  float lpt = lp + __shfl_xor(lp, 32, 64);
  float inv = 1.0f / lpt;

  unsigned short* ot = smem + wid * (32 * 72);
#pragma unroll
  for (int w = 0; w < 8; w++) {
    int reg = 2 * w;
    int dbase = (reg & 3) + 8 * (reg >> 2) + 4 * h;
    u32 p0 = cvt_pk_bf16(o0[reg] * inv, o0[reg + 1] * inv);
    u32 p1 = cvt_pk_bf16(o1[reg] * inv, o1[reg + 1] * inv);
    *(u32*)(ot + q * 72 + dbase) = p0;
    *(u32*)(ot + q * 72 + 32 + dbase) = p1;
  }
  __syncthreads();
  int row = lane >> 1, halfc = lane & 1;
  const unsigned short* src = ot + row * 72 + halfc * 32;
  unsigned short* dst = out + (size_t)(q0w + row) * NQ + head * 64 + halfc * 32;
#pragma unroll
  for (int c = 0; c < 4; c++)
    *(bf16x8*)(dst + c * 8) = *(const bf16x8*)(src + c * 8);
#undef STAGE_KV
}

// ---------------- launch ----------------
extern "C" void kernel_launch(void* const* d_in, const int* in_sizes, int n_in,
                              void* d_out, int out_size, void* d_ws, size_t ws_size,
                              hipStream_t stream) {
  const float* hidden = (const float*)d_in[0];
  const float* cosb = (const float*)d_in[1];
  const float* sinb = (const float*)d_in[2];
  const float* wq = (const float*)d_in[3];
  const float* wk = (const float*)d_in[4];
  const float* wv = (const float*)d_in[5];
  const float* wo = (const float*)d_in[6];
  float* out = (float*)d_out;

  unsigned short* hb = (unsigned short*)d_ws;               // 2048*5760
  unsigned short* qkv = hb + (size_t)SEQ * INSZ;            // 2048*5120
  unsigned short* wqkvT = qkv + (size_t)SEQ * NQKV;         // 5120*5760
  unsigned short* woT = wqkvT + (size_t)NQKV * INSZ;        // 2944*4096
  unsigned short* vt = woT + (size_t)HIDP * NQ;             // 512*2048
  unsigned short* attn = vt + (size_t)NKV * SEQ;            // 2048*4096

  k_convert<<<dim3(1024), dim3(256), 0, stream>>>(hidden, hb, SEQ * INSZ);
  k_tconv<<<dim3(INSZ / 64, NQ / 32), dim3(256), 0, stream>>>(wq, wqkvT, INSZ, NQ);
  k_tconv<<<dim3(INSZ / 64, NKV / 32), dim3(256), 0, stream>>>(
      wk, wqkvT + (size_t)NQ * INSZ, INSZ, NKV);
  k_tconv<<<dim3(INSZ / 64, NKV / 32), dim3(256), 0, stream>>>(
      wv, wqkvT + (size_t)(NQ + NKV) * INSZ, INSZ, NKV);
  k_tconv<<<dim3(NQ / 64, HIDP / 32), dim3(256), 0, stream>>>(wo, woT, NQ, HID);

  k_gemm_bt<unsigned short><<<dim3(SEQ / 128, NQKV / 128), dim3(256), 0, stream>>>(
      hb, wqkvT, qkv, INSZ, NQKV, NQKV);
  k_rope<<<dim3(SEQ), dim3(256), 0, stream>>>(qkv, cosb, sinb);
  k_vtrans<<<dim3(SEQ / 64, HKV), dim3(256), 0, stream>>>(qkv, vt);
  k_attn<<<dim3(HQ, SEQ / 128), dim3(256), 0, stream>>>(qkv, vt, attn);
  k_gemm_bt<float><<<dim3(SEQ / 128, (HID + 127) / 128), dim3(256), 0, stream>>>(
      attn, woT, out, NQ, HID, HID);
}